// Round 4
// baseline (47.924 us; speedup 1.0000x reference)
//
#include <hip/hip_runtime.h>

// IdentityConvolution: 1x1 conv, all-ones weight, complex input.
//   out[b,co,h,w] = sum_c x_real[b,c,h,w]   (harness compares real part only:
//   out_size = B*64*256*256 float32 = 128 MiB)
//
// R2 result: 44.45 us, FETCH=65.5MB (half of x_real already L3-resident
// across graph replays), WRITE=131MB. Input+output = 256 MiB = exactly L3
// capacity -> our own write stream evicts the input. This round: nontemporal
// (nt) stores so the write-once output no-allocates in L2/L3 and x_real
// stays L3-resident. Loads remain cached.
// R3 fix: __builtin_nontemporal_store needs a native clang vector type,
// not HIP's float4 class -> use ext_vector_type(4).

#define CHANNELS 64
#define HW (256 * 256)
#define HW4 (HW / 4)   // 16384 float4 groups per plane

typedef float f4 __attribute__((ext_vector_type(4)));

// ---- Path A: real part only. out[b,co,p] = sum_c xr[b,c,p] ----
__global__ __launch_bounds__(256)
void identity_conv_real_kernel(const f4* __restrict__ xr,
                               f4* __restrict__ out,
                               int total) {
    int gid = blockIdx.x * blockDim.x + threadIdx.x;
    if (gid >= total) return;

    int b  = gid >> 14;          // / HW4
    int p4 = gid & (HW4 - 1);

    const f4* xr_b = xr + (size_t)b * CHANNELS * HW4 + p4;

    f4 r = (f4)(0.f);
    #pragma unroll 16
    for (int c = 0; c < CHANNELS; ++c) {
        r += xr_b[(size_t)c * HW4];
    }

    f4* ob = out + (size_t)b * CHANNELS * HW4 + p4;
    #pragma unroll 16
    for (int co = 0; co < CHANNELS; ++co) {
        __builtin_nontemporal_store(r, &ob[(size_t)co * HW4]);
    }
}

// ---- Path B (fallback): interleaved complex64 pairs ----
__global__ __launch_bounds__(256)
void identity_conv_cplx_kernel(const f4* __restrict__ xr,
                               const f4* __restrict__ xi,
                               f4* __restrict__ out,
                               int total) {
    int gid = blockIdx.x * blockDim.x + threadIdx.x;
    if (gid >= total) return;

    int b  = gid >> 14;
    int p4 = gid & (HW4 - 1);

    const f4* xr_b = xr + (size_t)b * CHANNELS * HW4 + p4;
    const f4* xi_b = xi + (size_t)b * CHANNELS * HW4 + p4;

    f4 r  = (f4)(0.f);
    f4 im = (f4)(0.f);
    #pragma unroll 8
    for (int c = 0; c < CHANNELS; ++c) {
        r  += xr_b[(size_t)c * HW4];
        im += xi_b[(size_t)c * HW4];
    }

    f4 lo = (f4){r.x, im.x, r.y, im.y};
    f4 hi = (f4){r.z, im.z, r.w, im.w};

    f4* ob = out + (size_t)b * CHANNELS * (HW / 2) + (size_t)p4 * 2;
    #pragma unroll 4
    for (int co = 0; co < CHANNELS; ++co) {
        __builtin_nontemporal_store(lo, &ob[0]);
        __builtin_nontemporal_store(hi, &ob[1]);
        ob += HW / 2;
    }
}

extern "C" void kernel_launch(void* const* d_in, const int* in_sizes, int n_in,
                              void* d_out, int out_size, void* d_ws, size_t ws_size,
                              hipStream_t stream) {
    const f4* xr = (const f4*)d_in[0];
    const f4* xi = (const f4*)d_in[1];
    f4* out = (f4*)d_out;

    int n = in_sizes[0];                 // B * C * HW
    int B = n / (CHANNELS * HW);         // 8
    int total = B * HW4;                 // 131,072 threads

    const int block = 256;
    int grid = (total + block - 1) / block;

    if (out_size >= 2 * n) {
        identity_conv_cplx_kernel<<<grid, block, 0, stream>>>(xr, xi, out, total);
    } else {
        identity_conv_real_kernel<<<grid, block, 0, stream>>>(xr, out, total);
    }
}

// Round 5
// 46.598 us; speedup vs baseline: 1.0285x; 1.0285x over previous
//
#include <hip/hip_runtime.h>

// IdentityConvolution: 1x1 conv, all-ones weight, complex input.
//   out[b,co,h,w] = sum_c x_real[b,c,h,w]  (harness compares real part only:
//   out_size = B*64*256*256 float32 = 128 MiB)
//
// R2: 44.45 us @ 2 blocks/CU, FETCH=65.5MB (L3 covers half the input),
//     WRITE=131MB -> 4.4 TB/s effective, latency-bound (Occ 17.8%).
// R4: nt stores regressed (47.9 us, FETCH unchanged) -> reverted.
// R5: 4-way channel split WITHIN each wave. Each thread sums 16 channels,
//     quarters combine via 8 __shfl_xor (no LDS, no extra traffic), each
//     thread writes 16 output planes. 4x threads -> 2048 blocks = 8/CU =
//     32 waves/CU full occupancy; shorter read/write phases interleave.

#define CHANNELS 64
#define HW (256 * 256)
#define HW4 (HW / 4)   // 16384 float4 groups per plane

typedef float f4 __attribute__((ext_vector_type(4)));

// ---- Path A: real part only, 4-way wave-internal channel split ----
__global__ __launch_bounds__(256)
void identity_conv_real_kernel(const f4* __restrict__ xr,
                               f4* __restrict__ out,
                               int total_groups) {
    int tid  = threadIdx.x;
    int lane = tid & 63;
    int q    = lane >> 4;       // channel quarter 0..3
    int pl   = lane & 15;       // pixel-group offset within 16
    int wave = tid >> 6;        // wave within block 0..3

    // Each block covers 64 consecutive float4 groups: 4 waves x 16 each.
    int g = blockIdx.x * 64 + wave * 16 + pl;
    if (g >= total_groups) return;

    int b  = g >> 14;           // / HW4
    int p4 = g & (HW4 - 1);

    const f4* base = xr + (size_t)b * CHANNELS * HW4
                        + (size_t)(q * 16) * HW4 + p4;
    f4 r = (f4)(0.f);
    #pragma unroll 16
    for (int c = 0; c < 16; ++c)
        r += base[(size_t)c * HW4];

    // Combine the 4 quarter-sums (lane bits 4 and 5).
    r.x += __shfl_xor(r.x, 16);  r.y += __shfl_xor(r.y, 16);
    r.z += __shfl_xor(r.z, 16);  r.w += __shfl_xor(r.w, 16);
    r.x += __shfl_xor(r.x, 32);  r.y += __shfl_xor(r.y, 32);
    r.z += __shfl_xor(r.z, 32);  r.w += __shfl_xor(r.w, 32);

    // Each lane writes its 16 output-channel planes.
    f4* ob = out + (size_t)b * CHANNELS * HW4
                 + (size_t)(q * 16) * HW4 + p4;
    #pragma unroll 16
    for (int co = 0; co < 16; ++co)
        ob[(size_t)co * HW4] = r;
}

// ---- Path B (fallback): interleaved complex64 pairs ----
__global__ __launch_bounds__(256)
void identity_conv_cplx_kernel(const f4* __restrict__ xr,
                               const f4* __restrict__ xi,
                               f4* __restrict__ out,
                               int total) {
    int gid = blockIdx.x * blockDim.x + threadIdx.x;
    if (gid >= total) return;

    int b  = gid >> 14;
    int p4 = gid & (HW4 - 1);

    const f4* xr_b = xr + (size_t)b * CHANNELS * HW4 + p4;
    const f4* xi_b = xi + (size_t)b * CHANNELS * HW4 + p4;

    f4 r  = (f4)(0.f);
    f4 im = (f4)(0.f);
    #pragma unroll 8
    for (int c = 0; c < CHANNELS; ++c) {
        r  += xr_b[(size_t)c * HW4];
        im += xi_b[(size_t)c * HW4];
    }

    f4 lo = (f4){r.x, im.x, r.y, im.y};
    f4 hi = (f4){r.z, im.z, r.w, im.w};

    f4* ob = out + (size_t)b * CHANNELS * (HW / 2) + (size_t)p4 * 2;
    #pragma unroll 4
    for (int co = 0; co < CHANNELS; ++co) {
        ob[0] = lo;
        ob[1] = hi;
        ob += HW / 2;
    }
}

extern "C" void kernel_launch(void* const* d_in, const int* in_sizes, int n_in,
                              void* d_out, int out_size, void* d_ws, size_t ws_size,
                              hipStream_t stream) {
    const f4* xr = (const f4*)d_in[0];
    const f4* xi = (const f4*)d_in[1];
    f4* out = (f4*)d_out;

    int n = in_sizes[0];                 // B * C * HW
    int B = n / (CHANNELS * HW);         // 8
    int total = B * HW4;                 // 131,072 float4 groups

    if (out_size >= 2 * n) {
        const int block = 256;
        int grid = (total + block - 1) / block;
        identity_conv_cplx_kernel<<<grid, block, 0, stream>>>(xr, xi, out, total);
    } else {
        // 4 threads per float4 group -> 64 groups per 256-thread block
        int grid = (total + 63) / 64;    // 2048 blocks
        identity_conv_real_kernel<<<grid, 256, 0, stream>>>(xr, out, total);
    }
}